// Round 8
// baseline (3741.433 us; speedup 1.0000x reference)
//
#include <hip/hip_runtime.h>
#include <math.h>

#define NB      8      // batch rows per workgroup in passA/passB
#define NBC     2      // batch rows per workgroup in combine
#define CHUNKS  64     // time chunks (L = T/CHUNKS = 16)
#define LIM     0x1p100f
#define RESCALE_THRESH 0x1p44f
#define SCL_DN  0x1p-40f

// 4x4 k-block MAC: acc (float4, 4 cols) += S-broadcast (float4, 4 k) * R rows
#define MAC_ROW(A, SV, RV)                                                \
    A.x = fmaf(SV.x, RV[0].x, A.x); A.y = fmaf(SV.x, RV[0].y, A.y);       \
    A.z = fmaf(SV.x, RV[0].z, A.z); A.w = fmaf(SV.x, RV[0].w, A.w);       \
    A.x = fmaf(SV.y, RV[1].x, A.x); A.y = fmaf(SV.y, RV[1].y, A.y);       \
    A.z = fmaf(SV.y, RV[1].z, A.z); A.w = fmaf(SV.y, RV[1].w, A.w);       \
    A.x = fmaf(SV.z, RV[2].x, A.x); A.y = fmaf(SV.z, RV[2].y, A.y);       \
    A.z = fmaf(SV.z, RV[2].z, A.z); A.w = fmaf(SV.z, RV[2].w, A.w);       \
    A.x = fmaf(SV.w, RV[3].x, A.x); A.y = fmaf(SV.w, RV[3].y, A.y);       \
    A.z = fmaf(SV.w, RV[3].z, A.z); A.w = fmaf(SV.w, RV[3].w, A.w);

// ---------------------------------------------------------------------------
// Generic tiled fp32 GEMM: C = A@B. A:[M,512], B:[512,512], C:[M,512].
// BM=BN=64, BK=16, 256 threads, 4x4 microtile, next-tile register prefetch.
// ---------------------------------------------------------------------------
#define BM 64
#define BN 64
#define BK 16

__global__ __launch_bounds__(256) void gemm_xk(const float* __restrict__ A,
                                               const float* __restrict__ B,
                                               float* __restrict__ C) {
    __shared__ float As[BK][BM + 4];
    __shared__ float Bs[BK][BN];

    const int tid  = threadIdx.x;
    const int col0 = blockIdx.x * BN;
    const int row0 = blockIdx.y * BM;

    const int tx = tid & 15;
    const int ty = tid >> 4;

    const int am = tid >> 2;
    const int ak = (tid & 3) << 2;
    const int bk  = tid >> 4;
    const int bn4 = (tid & 15) << 2;

    float acc[4][4] = {{0.f,0.f,0.f,0.f},{0.f,0.f,0.f,0.f},
                       {0.f,0.f,0.f,0.f},{0.f,0.f,0.f,0.f}};

    // prologue: load tile k0=0 into registers
    float4 av = *(const float4*)(A + (size_t)(row0 + am) * 512 + ak);
    float4 bv = *(const float4*)(B + (size_t)bk * 512 + (col0 + bn4));

    for (int k0 = 0; k0 < 512; k0 += BK) {
        __syncthreads();
        As[ak + 0][am] = av.x;
        As[ak + 1][am] = av.y;
        As[ak + 2][am] = av.z;
        As[ak + 3][am] = av.w;
        *(float4*)&Bs[bk][bn4] = bv;
        __syncthreads();
        if (k0 + BK < 512) {   // issue next-tile loads; they overlap the FMAs
            av = *(const float4*)(A + (size_t)(row0 + am) * 512 + (k0 + BK + ak));
            bv = *(const float4*)(B + (size_t)(k0 + BK + bk) * 512 + (col0 + bn4));
        }
#pragma unroll
        for (int k = 0; k < BK; ++k) {
            float4 a4 = *(const float4*)&As[k][ty << 2];
            float4 b4 = *(const float4*)&Bs[k][tx << 2];
            float ar[4] = {a4.x, a4.y, a4.z, a4.w};
            float br[4] = {b4.x, b4.y, b4.z, b4.w};
#pragma unroll
            for (int i = 0; i < 4; ++i)
#pragma unroll
                for (int j = 0; j < 4; ++j)
                    acc[i][j] = fmaf(ar[i], br[j], acc[i][j]);
        }
    }

#pragma unroll
    for (int i = 0; i < 4; ++i) {
        float4 v = make_float4(acc[i][0], acc[i][1], acc[i][2], acc[i][3]);
        *(float4*)(C + (size_t)(row0 + (ty << 2) + i) * 512 + col0 + (tx << 2)) = v;
    }
}

// ---------------------------------------------------------------------------
// Pass A: per (batch-group g of NB=8 rows, chunk c), local recurrence from
// ZERO state; store only y_end(c).
// W=256, row-split half-wg layout: rg = tid>>7 owns rows 4rg..4rg+3;
// cl = tid&127 owns 4 CONSECUTIVE cols 4cl..4cl+3. (R7-proven layout.)
// ---------------------------------------------------------------------------
__global__ __launch_bounds__(256) void passA(const float* __restrict__ U,
                                             const float* __restrict__ R,
                                             float* __restrict__ y_end,
                                             int T, int B) {
    __shared__ float S[NB][512];
    const int g   = blockIdx.x;
    const int c   = blockIdx.y;
    const int tid = threadIdx.x;
    const int rg  = tid >> 7;       // 0/1
    const int cl  = tid & 127;
    const int rb  = rg * 4;
    const int j4  = cl << 2;        // first owned column
    const int L   = T / CHUNKS;
    const int t0  = c * L;
    const int r0  = g * NB;

#pragma unroll
    for (int r = 0; r < 4; ++r)
        *(float4*)&S[rb + r][j4] = make_float4(0.f, 0.f, 0.f, 0.f);
    __syncthreads();

    const float* __restrict__ Rb = R + j4;

    for (int t = t0; t < t0 + L; ++t) {
        // prefetch U for this step (latency hides under the matvec)
        float4 u[4];
#pragma unroll
        for (int r = 0; r < 4; ++r)
            u[r] = *(const float4*)(U + ((size_t)(r0 + rb + r) * T + t) * 512 + j4);

        float4 acc[4];
#pragma unroll
        for (int r = 0; r < 4; ++r) acc[r] = make_float4(0.f, 0.f, 0.f, 0.f);

        float4 sA[4], sB[4], rvA[4], rvB[4];
#pragma unroll
        for (int r = 0; r < 4; ++r) sA[r] = *(const float4*)&S[rb + r][0];
#pragma unroll
        for (int kk = 0; kk < 4; ++kk)
            rvA[kk] = *(const float4*)(Rb + (size_t)kk * 512);

#pragma unroll 1
        for (int d = 0; d < 512; d += 8) {
            // prefetch B half (k = d+4 .. d+7)
            const float* RB_ = Rb + (size_t)(d + 4) * 512;
#pragma unroll
            for (int kk = 0; kk < 4; ++kk)
                rvB[kk] = *(const float4*)(RB_ + (size_t)kk * 512);
#pragma unroll
            for (int r = 0; r < 4; ++r) sB[r] = *(const float4*)&S[rb + r][d + 4];
            // FMA with A half (k = d .. d+3)
#pragma unroll
            for (int r = 0; r < 4; ++r) { MAC_ROW(acc[r], sA[r], rvA); }
            // prefetch next A half (k = d+8 .. d+11; wraps harmlessly at end)
            const int dA = (d + 8) & 511;
            const float* RA_ = Rb + (size_t)dA * 512;
#pragma unroll
            for (int kk = 0; kk < 4; ++kk)
                rvA[kk] = *(const float4*)(RA_ + (size_t)kk * 512);
#pragma unroll
            for (int r = 0; r < 4; ++r) sA[r] = *(const float4*)&S[rb + r][dA];
            // FMA with B half (k = d+4 .. d+7)
#pragma unroll
            for (int r = 0; r < 4; ++r) { MAC_ROW(acc[r], sB[r], rvB); }
        }
        __syncthreads();   // all reads of S complete
#pragma unroll
        for (int r = 0; r < 4; ++r) {
            float4 sn;
            sn.x = fminf(fmaxf(u[r].x + acc[r].x, -LIM), LIM);  // NaN-drop clamp
            sn.y = fminf(fmaxf(u[r].y + acc[r].y, -LIM), LIM);
            sn.z = fminf(fmaxf(u[r].z + acc[r].z, -LIM), LIM);
            sn.w = fminf(fmaxf(u[r].w + acc[r].w, -LIM), LIM);
            *(float4*)&S[rb + r][j4] = sn;
        }
        __syncthreads();
    }

#pragma unroll
    for (int r = 0; r < 4; ++r)
        *(float4*)(y_end + ((size_t)c * B + (r0 + rb + r)) * 512 + j4) =
            *(const float4*)&S[rb + r][j4];
}

// ---------------------------------------------------------------------------
// Combine: h(c) = y_end(c-1) + h(c-1) @ RL, block-floating-point scaled per
// (group g of NBC rows, c). h(c) written IN PLACE over y_end(c-1).
// W=512: rg = tid>>8 owns row r0+rg; cl = tid&255 owns cols {2cl, 2cl+1}.
// RL loads are float2 (coalesced, a wave covers a contiguous 512B of a row);
// S reads are wave-uniform broadcast float4s (0 bank conflicts).
// 4-deep ring pipeline over 8-k blocks: loads for block b+4 are issued while
// FMAing block b -> ~180 cyc issue distance covers L2 latency; x2 waves/SIMD.
// ---------------------------------------------------------------------------
__global__ __launch_bounds__(512) void combine(float* __restrict__ yeh,
                                               const float* __restrict__ s0,
                                               const float* __restrict__ RL,
                                               int* __restrict__ Eout,
                                               int B, int C) {
    __shared__ float S[NBC][512];
    __shared__ float red[8];
    const int g   = blockIdx.x;
    const int G   = gridDim.x;      // B / NBC
    const int tid = threadIdx.x;
    const int rg  = tid >> 8;       // 0/1: which of the NBC rows this lane owns
    const int cl  = tid & 255;      // column-pair index
    const int j2  = cl << 1;        // first owned column
    const int r0  = g * NBC;
    const int row = r0 + rg;

    {
        float2 v = *(const float2*)(s0 + (size_t)row * 512 + j2);
        v.x = fminf(fmaxf(v.x, -LIM), LIM);
        v.y = fminf(fmaxf(v.y, -LIM), LIM);
        *(float2*)&S[rg][j2] = v;
    }
    int E = 0;
    __syncthreads();

    const float2* __restrict__ RL2 = (const float2*)RL;   // [512][256] float2

    for (int c = 1; c < C; ++c) {
        // prefetch ye (consumed only after the matvec -> latency hidden)
        float2 ye = *(const float2*)(yeh + ((size_t)(c - 1) * B + row) * 512 + j2);

        float2 acc = make_float2(0.f, 0.f);
        float2 rv[4][8];               // ring: 4 blocks x 8 k-rows in flight
#pragma unroll
        for (int q = 0; q < 4; ++q)
#pragma unroll
            for (int kk = 0; kk < 8; ++kk)
                rv[q][kk] = RL2[(size_t)(8 * q + kk) * 256 + cl];

#pragma unroll 1
        for (int i = 0; i < 16; ++i) {
            const int b0 = i * 4;
#pragma unroll
            for (int q = 0; q < 4; ++q) {
                const int b = b0 + q;
                float2 t[8];
#pragma unroll
                for (int kk = 0; kk < 8; ++kk) t[kk] = rv[q][kk];
                const int pb = (b + 4) & 63;   // prefetch block (wraps harmlessly)
#pragma unroll
                for (int kk = 0; kk < 8; ++kk)
                    rv[q][kk] = RL2[(size_t)(8 * pb + kk) * 256 + cl];
                float4 sa = *(const float4*)&S[rg][8 * b];       // broadcast
                float4 sb = *(const float4*)&S[rg][8 * b + 4];   // broadcast
                acc.x = fmaf(sa.x, t[0].x, acc.x); acc.y = fmaf(sa.x, t[0].y, acc.y);
                acc.x = fmaf(sa.y, t[1].x, acc.x); acc.y = fmaf(sa.y, t[1].y, acc.y);
                acc.x = fmaf(sa.z, t[2].x, acc.x); acc.y = fmaf(sa.z, t[2].y, acc.y);
                acc.x = fmaf(sa.w, t[3].x, acc.x); acc.y = fmaf(sa.w, t[3].y, acc.y);
                acc.x = fmaf(sb.x, t[4].x, acc.x); acc.y = fmaf(sb.x, t[4].y, acc.y);
                acc.x = fmaf(sb.y, t[5].x, acc.x); acc.y = fmaf(sb.y, t[5].y, acc.y);
                acc.x = fmaf(sb.z, t[6].x, acc.x); acc.y = fmaf(sb.z, t[6].y, acc.y);
                acc.x = fmaf(sb.w, t[7].x, acc.x); acc.y = fmaf(sb.w, t[7].y, acc.y);
            }
        }

        float us = ldexpf(1.f, -40 * E);   // underflow to 0 is fine
        float2 tmp;
        tmp.x = fminf(fmaxf(fmaf(ye.x, us, acc.x), -LIM), LIM);
        tmp.y = fminf(fmaxf(fmaf(ye.y, us, acc.y), -LIM), LIM);
        float m = fmaxf(fabsf(tmp.x), fabsf(tmp.y));
#pragma unroll
        for (int o = 32; o > 0; o >>= 1) m = fmaxf(m, __shfl_xor(m, o));
        if ((tid & 63) == 0) red[tid >> 6] = m;
        __syncthreads();   // closes S-read phase AND publishes red[]
        m = fmaxf(fmaxf(fmaxf(red[0], red[1]), fmaxf(red[2], red[3])),
                  fmaxf(fmaxf(red[4], red[5]), fmaxf(red[6], red[7])));
        if (m > RESCALE_THRESH) {
            tmp.x *= SCL_DN; tmp.y *= SCL_DN;
            E += 1;
        }
        *(float2*)&S[rg][j2] = tmp;
        *(float2*)(yeh + ((size_t)(c - 1) * B + row) * 512 + j2) = tmp;  // h(c)
        if (tid == 0) Eout[c * G + g] = E;
        __syncthreads();
    }
}

// ---------------------------------------------------------------------------
// Pass B: per (g of NB=8 rows, c), TRUE recurrence over the chunk starting
// from h(c) (exponents unified to wg max at load), out = hopf(s) in f64.
// Same W=256 row-split/consecutive-col layout as passA; pipelined d-loop;
// shuffle-based rescale reduce.
// ---------------------------------------------------------------------------
__global__ __launch_bounds__(256) void passB(const float* __restrict__ R,
                                             const float* __restrict__ s0,
                                             const float* __restrict__ hbuf,
                                             const int* __restrict__ Ein,
                                             float* __restrict__ out,
                                             int T, int B, int Gc) {
    __shared__ float S[NB][512];
    __shared__ float red[4];
    const int g   = blockIdx.x;
    const int c   = blockIdx.y;
    const int tid = threadIdx.x;
    const int rg  = tid >> 7;
    const int cl  = tid & 127;
    const int rb  = rg * 4;
    const int j4  = cl << 2;
    const int L   = T / CHUNKS;
    const int t0  = c * L;
    const int r0  = g * NB;

    int E = 0;
    if (c == 0) {
#pragma unroll
        for (int r = 0; r < 4; ++r) {
            float4 v = *(const float4*)(s0 + (size_t)(r0 + rb + r) * 512 + j4);
            v.x = fminf(fmaxf(v.x, -LIM), LIM);
            v.y = fminf(fmaxf(v.y, -LIM), LIM);
            v.z = fminf(fmaxf(v.z, -LIM), LIM);
            v.w = fminf(fmaxf(v.w, -LIM), LIM);
            *(float4*)&S[rb + r][j4] = v;
        }
    } else {
        int Ep[NB / NBC];
        int Em = 0;
#pragma unroll
        for (int p = 0; p < NB / NBC; ++p) {
            Ep[p] = Ein[c * Gc + (r0 / NBC) + p];
            Em = (Ep[p] > Em) ? Ep[p] : Em;
        }
#pragma unroll
        for (int r = 0; r < 4; ++r) {
            int Er = Ep[(rb + r) / NBC];
            float f = (Er == Em) ? 1.f : ldexpf(1.f, 40 * (Er - Em));
            float4 v = *(const float4*)(hbuf + ((size_t)(c - 1) * B + (r0 + rb + r)) * 512 + j4);
            v.x *= f; v.y *= f; v.z *= f; v.w *= f;
            *(float4*)&S[rb + r][j4] = v;
        }
        E = Em;
    }
    __syncthreads();

    double scaleE = ldexp(1.0, 40 * E);
    float  uscale = ldexpf(1.f, -40 * E);

    const float* __restrict__ Rb = R + j4;

    for (int t = t0; t < t0 + L; ++t) {
        // prefetch U (current out values) for this step
        float4 u[4];
        size_t ob[4];
#pragma unroll
        for (int r = 0; r < 4; ++r) {
            size_t base = ((size_t)(r0 + rb + r) * T + t) * 512 + j4;
            ob[r] = base;
            u[r] = *(const float4*)(out + base);
        }

        float4 acc[4];
#pragma unroll
        for (int r = 0; r < 4; ++r) acc[r] = make_float4(0.f, 0.f, 0.f, 0.f);

        float4 sA[4], sB[4], rvA[4], rvB[4];
#pragma unroll
        for (int r = 0; r < 4; ++r) sA[r] = *(const float4*)&S[rb + r][0];
#pragma unroll
        for (int kk = 0; kk < 4; ++kk)
            rvA[kk] = *(const float4*)(Rb + (size_t)kk * 512);

#pragma unroll 1
        for (int d = 0; d < 512; d += 8) {
            const float* RB_ = Rb + (size_t)(d + 4) * 512;
#pragma unroll
            for (int kk = 0; kk < 4; ++kk)
                rvB[kk] = *(const float4*)(RB_ + (size_t)kk * 512);
#pragma unroll
            for (int r = 0; r < 4; ++r) sB[r] = *(const float4*)&S[rb + r][d + 4];
#pragma unroll
            for (int r = 0; r < 4; ++r) { MAC_ROW(acc[r], sA[r], rvA); }
            const int dA = (d + 8) & 511;
            const float* RA_ = Rb + (size_t)dA * 512;
#pragma unroll
            for (int kk = 0; kk < 4; ++kk)
                rvA[kk] = *(const float4*)(RA_ + (size_t)kk * 512);
#pragma unroll
            for (int r = 0; r < 4; ++r) sA[r] = *(const float4*)&S[rb + r][dA];
#pragma unroll
            for (int r = 0; r < 4; ++r) { MAC_ROW(acc[r], sB[r], rvB); }
        }

        float4 sn[4];
        float mx = 0.f;
#pragma unroll
        for (int r = 0; r < 4; ++r) {
            float4 vv;
            vv.x = fminf(fmaxf(fmaf(u[r].x, uscale, acc[r].x), -LIM), LIM);
            vv.y = fminf(fmaxf(fmaf(u[r].y, uscale, acc[r].y), -LIM), LIM);
            vv.z = fminf(fmaxf(fmaf(u[r].z, uscale, acc[r].z), -LIM), LIM);
            vv.w = fminf(fmaxf(fmaf(u[r].w, uscale, acc[r].w), -LIM), LIM);
            sn[r] = vv;
            mx = fmaxf(mx, fmaxf(fmaxf(fabsf(vv.x), fabsf(vv.y)),
                                 fmaxf(fabsf(vv.z), fabsf(vv.w))));
            float4 o4;
            {
                double sd = (double)vv.x * scaleE;
                double ov = sd * (1.0 - sd * sd);
                double oc = fmin(fmax(ov, -3.0e38), 3.0e38);
                o4.x = (float)((oc == oc) ? oc : 0.0);
            }
            {
                double sd = (double)vv.y * scaleE;
                double ov = sd * (1.0 - sd * sd);
                double oc = fmin(fmax(ov, -3.0e38), 3.0e38);
                o4.y = (float)((oc == oc) ? oc : 0.0);
            }
            {
                double sd = (double)vv.z * scaleE;
                double ov = sd * (1.0 - sd * sd);
                double oc = fmin(fmax(ov, -3.0e38), 3.0e38);
                o4.z = (float)((oc == oc) ? oc : 0.0);
            }
            {
                double sd = (double)vv.w * scaleE;
                double ov = sd * (1.0 - sd * sd);
                double oc = fmin(fmax(ov, -3.0e38), 3.0e38);
                o4.w = (float)((oc == oc) ? oc : 0.0);
            }
            *(float4*)(out + ob[r]) = o4;
        }

        if ((t & 7) == 7) {      // periodic rescale (uniform branch)
            float m = mx;
#pragma unroll
            for (int o = 32; o > 0; o >>= 1) m = fmaxf(m, __shfl_xor(m, o));
            if ((tid & 63) == 0) red[tid >> 6] = m;
            __syncthreads();     // closes S-read phase AND publishes red[]
            m = fmaxf(fmaxf(red[0], red[1]), fmaxf(red[2], red[3]));
            if (m > RESCALE_THRESH) {
#pragma unroll
                for (int r = 0; r < 4; ++r) {
                    sn[r].x *= SCL_DN; sn[r].y *= SCL_DN;
                    sn[r].z *= SCL_DN; sn[r].w *= SCL_DN;
                }
                E += 1;
                scaleE *= 0x1p40;
                uscale *= SCL_DN;
            }
        } else {
            __syncthreads();     // close read phase before overwriting S
        }
#pragma unroll
        for (int r = 0; r < 4; ++r) *(float4*)&S[rb + r][j4] = sn[r];
        __syncthreads();
    }
}

// ---------------------------------------------------------------------------
// Fallback (proven path): single-pass sequential recurrence.
// ---------------------------------------------------------------------------
__global__ __launch_bounds__(512) void recur(const float* __restrict__ R,
                                             const float* __restrict__ s0,
                                             float* __restrict__ out,
                                             int T) {
    __shared__ float sbuf[2][512];
    __shared__ float red[512];

    const int b = blockIdx.x;
    const int j = threadIdx.x;

    float sini = s0[(size_t)b * 512 + j];
    sbuf[0][j] = fminf(fmaxf(sini, -LIM), LIM);
    __syncthreads();

    const float* __restrict__ Rc = R + j;
    float* __restrict__ ob = out + (size_t)b * T * 512;

    int cur = 0;
    double scaleE = 1.0;
    float  uscale = 1.0f;

    for (int t = 0; t < T; ++t) {
        const float* s = sbuf[cur];
        float d0 = 0.f, d1 = 0.f, d2 = 0.f, d3 = 0.f;
#pragma unroll 8
        for (int d = 0; d < 512; d += 4) {
            d0 = fmaf(s[d + 0], Rc[(size_t)(d + 0) * 512], d0);
            d1 = fmaf(s[d + 1], Rc[(size_t)(d + 1) * 512], d1);
            d2 = fmaf(s[d + 2], Rc[(size_t)(d + 2) * 512], d2);
            d3 = fmaf(s[d + 3], Rc[(size_t)(d + 3) * 512], d3);
        }
        float u = ob[(size_t)t * 512 + j];
        float snew = fmaf(u, uscale, (d0 + d1) + (d2 + d3));
        snew = fminf(fmaxf(snew, -LIM), LIM);

        double sd = (double)snew * scaleE;
        double ov = sd * (1.0 - sd * sd);
        double oc = fmin(fmax(ov, -3.0e38), 3.0e38);
        oc = (oc == oc) ? oc : 0.0;
        ob[(size_t)t * 512 + j] = (float)oc;

        if ((t & 31) == 31) {
            red[j] = fabsf(snew);
            __syncthreads();
#pragma unroll
            for (int w = 256; w > 0; w >>= 1) {
                if (j < w) red[j] = fmaxf(red[j], red[j + w]);
                __syncthreads();
            }
            float m = red[0];
            __syncthreads();
            if (m > RESCALE_THRESH) {
                snew   *= SCL_DN;
                scaleE *= 0x1p40;
                uscale *= SCL_DN;
            }
        }

        sbuf[cur ^ 1][j] = snew;
        __syncthreads();
        cur ^= 1;
    }
}

// ---------------------------------------------------------------------------
extern "C" void kernel_launch(void* const* d_in, const int* in_sizes, int n_in,
                              void* d_out, int out_size, void* d_ws, size_t ws_size,
                              hipStream_t stream) {
    const float* x  = (const float*)d_in[0];  // [B, T, 512]
    const float* K  = (const float*)d_in[1];  // [512, 512]
    const float* R  = (const float*)d_in[2];  // [512, 512]
    const float* s0 = (const float*)d_in[3];  // [B, 512]
    float* out = (float*)d_out;               // [B, T, 512]

    const int D = 512;
    const int M = in_sizes[0] / D;   // B*T
    const int B = in_sizes[3] / D;   // 64
    const int T = M / B;             // 1024
    const int G  = B / NB;           // 8 batch groups (passA/passB)
    const int Gc = B / NBC;          // 32 combine groups

    // Phase 1: U = X@K into d_out (both paths need it).
    gemm_xk<<<dim3(D / BN, M / BM), 256, 0, stream>>>(x, K, out);

    // Workspace layout (bytes):
    //   [0, 1MB)   RLa (R^2, R^8)
    //   [1, 2MB)   RLb (R^4, R^16)
    //   [2, 10MB)  yeh: CHUNKS slots of B*D floats. Slot c (c<CHUNKS-1) holds
    //              y_end(c), later overwritten in place by h(c+1).
    //              Slot CHUNKS-1 hosts Ebuf (8 KB).
    const size_t MB = 1u << 20;
    const size_t slot = (size_t)B * D * sizeof(float);        // 128 KB
    const size_t off_RLa = 0;
    const size_t off_RLb = 1 * MB;
    const size_t off_yeh = 2 * MB;
    const size_t off_E   = off_yeh + (size_t)(CHUNKS - 1) * slot;
    const size_t need    = off_yeh + (size_t)CHUNKS * slot;   // 10 MB for B=64

    if (ws_size < need || (T % CHUNKS) != 0 || (B % NB) != 0 || (B % NBC) != 0 ||
        D != 512 || (size_t)CHUNKS * Gc * sizeof(int) > slot) {
        // Fallback: proven single-pass path.
        recur<<<B, D, 0, stream>>>(R, s0, out, T);
        return;
    }

    char* ws = (char*)d_ws;
    float* RLa  = (float*)(ws + off_RLa);
    float* RLb  = (float*)(ws + off_RLb);
    float* yeh  = (float*)(ws + off_yeh);
    int*   Ebuf = (int*)(ws + off_E);

    // Phase 2: RL = R^L by repeated squaring (L = T/CHUNKS = 16 = 2^4).
    dim3 sq(D / BN, D / BM);
    gemm_xk<<<sq, 256, 0, stream>>>(R,   R,   RLa);   // R^2
    gemm_xk<<<sq, 256, 0, stream>>>(RLa, RLa, RLb);   // R^4
    gemm_xk<<<sq, 256, 0, stream>>>(RLb, RLb, RLa);   // R^8
    gemm_xk<<<sq, 256, 0, stream>>>(RLa, RLa, RLb);   // R^16

    // Phase 3: local chunk endpoints (chunk CHUNKS-1's endpoint is unused).
    passA<<<dim3(G, CHUNKS - 1), 256, 0, stream>>>(out, R, yeh, T, B);

    // Phase 4: sequential combine across chunks (h in place + per-chunk exponent).
    combine<<<Gc, 512, 0, stream>>>(yeh, s0, RLb, Ebuf, B, CHUNKS);

    // Phase 5: true recurrence per chunk + hopf output.
    passB<<<dim3(G, CHUNKS), 256, 0, stream>>>(R, s0, yeh, Ebuf, out, T, B, Gc);
}

// Round 9
// 2463.591 us; speedup vs baseline: 1.5187x; 1.5187x over previous
//
#include <hip/hip_runtime.h>
#include <math.h>

#define NB      8      // batch rows per workgroup in passA/passB
#define NBC     2      // batch rows per workgroup in combine
#define CHUNKS  64     // time chunks (L = T/CHUNKS = 16)
#define LIM     0x1p100f
#define RESCALE_THRESH 0x1p44f
#define SCL_DN  0x1p-40f

// 4x4 k-block MAC: acc (float4, 4 cols) += S-broadcast (float4, 4 k) * R rows
#define MAC_ROW(A, SV, RV)                                                \
    A.x = fmaf(SV.x, RV[0].x, A.x); A.y = fmaf(SV.x, RV[0].y, A.y);       \
    A.z = fmaf(SV.x, RV[0].z, A.z); A.w = fmaf(SV.x, RV[0].w, A.w);       \
    A.x = fmaf(SV.y, RV[1].x, A.x); A.y = fmaf(SV.y, RV[1].y, A.y);       \
    A.z = fmaf(SV.y, RV[1].z, A.z); A.w = fmaf(SV.y, RV[1].w, A.w);       \
    A.x = fmaf(SV.z, RV[2].x, A.x); A.y = fmaf(SV.z, RV[2].y, A.y);       \
    A.z = fmaf(SV.z, RV[2].z, A.z); A.w = fmaf(SV.z, RV[2].w, A.w);       \
    A.x = fmaf(SV.w, RV[3].x, A.x); A.y = fmaf(SV.w, RV[3].y, A.y);       \
    A.z = fmaf(SV.w, RV[3].z, A.z); A.w = fmaf(SV.w, RV[3].w, A.w);

// ---------------------------------------------------------------------------
// Generic tiled fp32 GEMM: C = A@B. A:[M,512], B:[512,512], C:[M,512].
// BM=BN=64, BK=16, 256 threads, 4x4 microtile, next-tile register prefetch.
// ---------------------------------------------------------------------------
#define BM 64
#define BN 64
#define BK 16

__global__ __launch_bounds__(256) void gemm_xk(const float* __restrict__ A,
                                               const float* __restrict__ B,
                                               float* __restrict__ C) {
    __shared__ float As[BK][BM + 4];
    __shared__ float Bs[BK][BN];

    const int tid  = threadIdx.x;
    const int col0 = blockIdx.x * BN;
    const int row0 = blockIdx.y * BM;

    const int tx = tid & 15;
    const int ty = tid >> 4;

    const int am = tid >> 2;
    const int ak = (tid & 3) << 2;
    const int bk  = tid >> 4;
    const int bn4 = (tid & 15) << 2;

    float acc[4][4] = {{0.f,0.f,0.f,0.f},{0.f,0.f,0.f,0.f},
                       {0.f,0.f,0.f,0.f},{0.f,0.f,0.f,0.f}};

    // prologue: load tile k0=0 into registers
    float4 av = *(const float4*)(A + (size_t)(row0 + am) * 512 + ak);
    float4 bv = *(const float4*)(B + (size_t)bk * 512 + (col0 + bn4));

    for (int k0 = 0; k0 < 512; k0 += BK) {
        __syncthreads();
        As[ak + 0][am] = av.x;
        As[ak + 1][am] = av.y;
        As[ak + 2][am] = av.z;
        As[ak + 3][am] = av.w;
        *(float4*)&Bs[bk][bn4] = bv;
        __syncthreads();
        if (k0 + BK < 512) {   // issue next-tile loads; they overlap the FMAs
            av = *(const float4*)(A + (size_t)(row0 + am) * 512 + (k0 + BK + ak));
            bv = *(const float4*)(B + (size_t)(k0 + BK + bk) * 512 + (col0 + bn4));
        }
#pragma unroll
        for (int k = 0; k < BK; ++k) {
            float4 a4 = *(const float4*)&As[k][ty << 2];
            float4 b4 = *(const float4*)&Bs[k][tx << 2];
            float ar[4] = {a4.x, a4.y, a4.z, a4.w};
            float br[4] = {b4.x, b4.y, b4.z, b4.w};
#pragma unroll
            for (int i = 0; i < 4; ++i)
#pragma unroll
                for (int j = 0; j < 4; ++j)
                    acc[i][j] = fmaf(ar[i], br[j], acc[i][j]);
        }
    }

#pragma unroll
    for (int i = 0; i < 4; ++i) {
        float4 v = make_float4(acc[i][0], acc[i][1], acc[i][2], acc[i][3]);
        *(float4*)(C + (size_t)(row0 + (ty << 2) + i) * 512 + col0 + (tx << 2)) = v;
    }
}

// ---------------------------------------------------------------------------
// Pass A: per (batch-group g of NB=8 rows, chunk c), local recurrence from
// ZERO state; store only y_end(c).
// W=256, row-split half-wg layout: rg = tid>>7 owns rows 4rg..4rg+3;
// cl = tid&127 owns 4 CONSECUTIVE cols 4cl..4cl+3. (R7-proven layout.)
// ---------------------------------------------------------------------------
__global__ __launch_bounds__(256) void passA(const float* __restrict__ U,
                                             const float* __restrict__ R,
                                             float* __restrict__ y_end,
                                             int T, int B) {
    __shared__ float S[NB][512];
    const int g   = blockIdx.x;
    const int c   = blockIdx.y;
    const int tid = threadIdx.x;
    const int rg  = tid >> 7;       // 0/1
    const int cl  = tid & 127;
    const int rb  = rg * 4;
    const int j4  = cl << 2;        // first owned column
    const int L   = T / CHUNKS;
    const int t0  = c * L;
    const int r0  = g * NB;

#pragma unroll
    for (int r = 0; r < 4; ++r)
        *(float4*)&S[rb + r][j4] = make_float4(0.f, 0.f, 0.f, 0.f);
    __syncthreads();

    const float* __restrict__ Rb = R + j4;

    for (int t = t0; t < t0 + L; ++t) {
        // prefetch U for this step (latency hides under the matvec)
        float4 u[4];
#pragma unroll
        for (int r = 0; r < 4; ++r)
            u[r] = *(const float4*)(U + ((size_t)(r0 + rb + r) * T + t) * 512 + j4);

        float4 acc[4];
#pragma unroll
        for (int r = 0; r < 4; ++r) acc[r] = make_float4(0.f, 0.f, 0.f, 0.f);

        float4 sA[4], sB[4], rvA[4], rvB[4];
#pragma unroll
        for (int r = 0; r < 4; ++r) sA[r] = *(const float4*)&S[rb + r][0];
#pragma unroll
        for (int kk = 0; kk < 4; ++kk)
            rvA[kk] = *(const float4*)(Rb + (size_t)kk * 512);

#pragma unroll 1
        for (int d = 0; d < 512; d += 8) {
            // prefetch B half (k = d+4 .. d+7)
            const float* RB_ = Rb + (size_t)(d + 4) * 512;
#pragma unroll
            for (int kk = 0; kk < 4; ++kk)
                rvB[kk] = *(const float4*)(RB_ + (size_t)kk * 512);
#pragma unroll
            for (int r = 0; r < 4; ++r) sB[r] = *(const float4*)&S[rb + r][d + 4];
            // FMA with A half (k = d .. d+3)
#pragma unroll
            for (int r = 0; r < 4; ++r) { MAC_ROW(acc[r], sA[r], rvA); }
            // prefetch next A half (k = d+8 .. d+11; wraps harmlessly at end)
            const int dA = (d + 8) & 511;
            const float* RA_ = Rb + (size_t)dA * 512;
#pragma unroll
            for (int kk = 0; kk < 4; ++kk)
                rvA[kk] = *(const float4*)(RA_ + (size_t)kk * 512);
#pragma unroll
            for (int r = 0; r < 4; ++r) sA[r] = *(const float4*)&S[rb + r][dA];
            // FMA with B half (k = d+4 .. d+7)
#pragma unroll
            for (int r = 0; r < 4; ++r) { MAC_ROW(acc[r], sB[r], rvB); }
        }
        __syncthreads();   // all reads of S complete
#pragma unroll
        for (int r = 0; r < 4; ++r) {
            float4 sn;
            sn.x = fminf(fmaxf(u[r].x + acc[r].x, -LIM), LIM);  // NaN-drop clamp
            sn.y = fminf(fmaxf(u[r].y + acc[r].y, -LIM), LIM);
            sn.z = fminf(fmaxf(u[r].z + acc[r].z, -LIM), LIM);
            sn.w = fminf(fmaxf(u[r].w + acc[r].w, -LIM), LIM);
            *(float4*)&S[rb + r][j4] = sn;
        }
        __syncthreads();
    }

#pragma unroll
    for (int r = 0; r < 4; ++r)
        *(float4*)(y_end + ((size_t)c * B + (r0 + rb + r)) * 512 + j4) =
            *(const float4*)&S[rb + r][j4];
}

// ---------------------------------------------------------------------------
// Combine: h(c) = y_end(c-1) + h(c-1) @ RL, block-floating-point scaled per
// (group g of NBC rows, c). h(c) written IN PLACE over y_end(c-1).
// R7-proven structure (lane j owns column j for both rows; scalar RL loads;
// wave-uniform LDS broadcasts; shuffle rescale reduce). ONLY change vs R7:
//   - #pragma unroll 16 (64 independent RL loads in the scheduler window ->
//     8 exposed L2 latencies per step instead of 32)
//   - ye prefetched at step top (its latency hides under the matvec)
// NO manual pipelining (R8 lesson: rings/copies defeat the compiler).
// ---------------------------------------------------------------------------
__global__ __launch_bounds__(512) void combine(float* __restrict__ yeh,
                                               const float* __restrict__ s0,
                                               const float* __restrict__ RL,
                                               int* __restrict__ Eout,
                                               int B, int C) {
    __shared__ float S[NBC][512];
    __shared__ float red[8];
    const int g  = blockIdx.x;
    const int G  = gridDim.x;       // B / NBC
    const int j  = threadIdx.x;
    const int r0 = g * NBC;

#pragma unroll
    for (int r = 0; r < NBC; ++r) {
        float v = s0[(size_t)(r0 + r) * 512 + j];
        S[r][j] = fminf(fmaxf(v, -LIM), LIM);
    }
    int E = 0;
    __syncthreads();

    const float* __restrict__ RLc = RL + j;

    for (int c = 1; c < C; ++c) {
        // prefetch ye for this step (consumed after the matvec)
        float ye[NBC];
#pragma unroll
        for (int r = 0; r < NBC; ++r)
            ye[r] = yeh[((size_t)(c - 1) * B + (r0 + r)) * 512 + j];

        float acc[NBC] = {0.f, 0.f};
#pragma unroll 16
        for (int d = 0; d < 512; d += 4) {
            float rv0 = RLc[(size_t)(d + 0) * 512];
            float rv1 = RLc[(size_t)(d + 1) * 512];
            float rv2 = RLc[(size_t)(d + 2) * 512];
            float rv3 = RLc[(size_t)(d + 3) * 512];
#pragma unroll
            for (int r = 0; r < NBC; ++r) {
                float4 s4 = *(const float4*)&S[r][d];
                acc[r] = fmaf(s4.x, rv0, acc[r]);
                acc[r] = fmaf(s4.y, rv1, acc[r]);
                acc[r] = fmaf(s4.z, rv2, acc[r]);
                acc[r] = fmaf(s4.w, rv3, acc[r]);
            }
        }
        float us = ldexpf(1.f, -40 * E);   // underflow to 0 is fine
        float tmp[NBC];
        float mx = 0.f;
#pragma unroll
        for (int r = 0; r < NBC; ++r) {
            float sn = fminf(fmaxf(fmaf(ye[r], us, acc[r]), -LIM), LIM);
            tmp[r] = sn;
            mx = fmaxf(mx, fabsf(sn));
        }
        // wave-level max reduce, then cross-wave via 8-slot LDS
        float m = mx;
#pragma unroll
        for (int o = 32; o > 0; o >>= 1) m = fmaxf(m, __shfl_xor(m, o));
        if ((j & 63) == 0) red[j >> 6] = m;
        __syncthreads();   // closes S-read phase AND publishes red[]
        m = fmaxf(fmaxf(fmaxf(red[0], red[1]), fmaxf(red[2], red[3])),
                  fmaxf(fmaxf(red[4], red[5]), fmaxf(red[6], red[7])));
        if (m > RESCALE_THRESH) {
#pragma unroll
            for (int r = 0; r < NBC; ++r) tmp[r] *= SCL_DN;
            E += 1;
        }
#pragma unroll
        for (int r = 0; r < NBC; ++r) {
            S[r][j] = tmp[r];
            yeh[((size_t)(c - 1) * B + (r0 + r)) * 512 + j] = tmp[r];  // h(c)
        }
        if (j == 0) Eout[c * G + g] = E;
        __syncthreads();
    }
}

// ---------------------------------------------------------------------------
// Pass B: per (g of NB=8 rows, c), TRUE recurrence over the chunk starting
// from h(c) (exponents unified to wg max at load), out = hopf(s) in f64.
// Same W=256 row-split/consecutive-col layout as passA; pipelined d-loop;
// shuffle-based rescale reduce.
// ---------------------------------------------------------------------------
__global__ __launch_bounds__(256) void passB(const float* __restrict__ R,
                                             const float* __restrict__ s0,
                                             const float* __restrict__ hbuf,
                                             const int* __restrict__ Ein,
                                             float* __restrict__ out,
                                             int T, int B, int Gc) {
    __shared__ float S[NB][512];
    __shared__ float red[4];
    const int g   = blockIdx.x;
    const int c   = blockIdx.y;
    const int tid = threadIdx.x;
    const int rg  = tid >> 7;
    const int cl  = tid & 127;
    const int rb  = rg * 4;
    const int j4  = cl << 2;
    const int L   = T / CHUNKS;
    const int t0  = c * L;
    const int r0  = g * NB;

    int E = 0;
    if (c == 0) {
#pragma unroll
        for (int r = 0; r < 4; ++r) {
            float4 v = *(const float4*)(s0 + (size_t)(r0 + rb + r) * 512 + j4);
            v.x = fminf(fmaxf(v.x, -LIM), LIM);
            v.y = fminf(fmaxf(v.y, -LIM), LIM);
            v.z = fminf(fmaxf(v.z, -LIM), LIM);
            v.w = fminf(fmaxf(v.w, -LIM), LIM);
            *(float4*)&S[rb + r][j4] = v;
        }
    } else {
        int Ep[NB / NBC];
        int Em = 0;
#pragma unroll
        for (int p = 0; p < NB / NBC; ++p) {
            Ep[p] = Ein[c * Gc + (r0 / NBC) + p];
            Em = (Ep[p] > Em) ? Ep[p] : Em;
        }
#pragma unroll
        for (int r = 0; r < 4; ++r) {
            int Er = Ep[(rb + r) / NBC];
            float f = (Er == Em) ? 1.f : ldexpf(1.f, 40 * (Er - Em));
            float4 v = *(const float4*)(hbuf + ((size_t)(c - 1) * B + (r0 + rb + r)) * 512 + j4);
            v.x *= f; v.y *= f; v.z *= f; v.w *= f;
            *(float4*)&S[rb + r][j4] = v;
        }
        E = Em;
    }
    __syncthreads();

    double scaleE = ldexp(1.0, 40 * E);
    float  uscale = ldexpf(1.f, -40 * E);

    const float* __restrict__ Rb = R + j4;

    for (int t = t0; t < t0 + L; ++t) {
        // prefetch U (current out values) for this step
        float4 u[4];
        size_t ob[4];
#pragma unroll
        for (int r = 0; r < 4; ++r) {
            size_t base = ((size_t)(r0 + rb + r) * T + t) * 512 + j4;
            ob[r] = base;
            u[r] = *(const float4*)(out + base);
        }

        float4 acc[4];
#pragma unroll
        for (int r = 0; r < 4; ++r) acc[r] = make_float4(0.f, 0.f, 0.f, 0.f);

        float4 sA[4], sB[4], rvA[4], rvB[4];
#pragma unroll
        for (int r = 0; r < 4; ++r) sA[r] = *(const float4*)&S[rb + r][0];
#pragma unroll
        for (int kk = 0; kk < 4; ++kk)
            rvA[kk] = *(const float4*)(Rb + (size_t)kk * 512);

#pragma unroll 1
        for (int d = 0; d < 512; d += 8) {
            const float* RB_ = Rb + (size_t)(d + 4) * 512;
#pragma unroll
            for (int kk = 0; kk < 4; ++kk)
                rvB[kk] = *(const float4*)(RB_ + (size_t)kk * 512);
#pragma unroll
            for (int r = 0; r < 4; ++r) sB[r] = *(const float4*)&S[rb + r][d + 4];
#pragma unroll
            for (int r = 0; r < 4; ++r) { MAC_ROW(acc[r], sA[r], rvA); }
            const int dA = (d + 8) & 511;
            const float* RA_ = Rb + (size_t)dA * 512;
#pragma unroll
            for (int kk = 0; kk < 4; ++kk)
                rvA[kk] = *(const float4*)(RA_ + (size_t)kk * 512);
#pragma unroll
            for (int r = 0; r < 4; ++r) sA[r] = *(const float4*)&S[rb + r][dA];
#pragma unroll
            for (int r = 0; r < 4; ++r) { MAC_ROW(acc[r], sB[r], rvB); }
        }

        float4 sn[4];
        float mx = 0.f;
#pragma unroll
        for (int r = 0; r < 4; ++r) {
            float4 vv;
            vv.x = fminf(fmaxf(fmaf(u[r].x, uscale, acc[r].x), -LIM), LIM);
            vv.y = fminf(fmaxf(fmaf(u[r].y, uscale, acc[r].y), -LIM), LIM);
            vv.z = fminf(fmaxf(fmaf(u[r].z, uscale, acc[r].z), -LIM), LIM);
            vv.w = fminf(fmaxf(fmaf(u[r].w, uscale, acc[r].w), -LIM), LIM);
            sn[r] = vv;
            mx = fmaxf(mx, fmaxf(fmaxf(fabsf(vv.x), fabsf(vv.y)),
                                 fmaxf(fabsf(vv.z), fabsf(vv.w))));
            float4 o4;
            {
                double sd = (double)vv.x * scaleE;
                double ov = sd * (1.0 - sd * sd);
                double oc = fmin(fmax(ov, -3.0e38), 3.0e38);
                o4.x = (float)((oc == oc) ? oc : 0.0);
            }
            {
                double sd = (double)vv.y * scaleE;
                double ov = sd * (1.0 - sd * sd);
                double oc = fmin(fmax(ov, -3.0e38), 3.0e38);
                o4.y = (float)((oc == oc) ? oc : 0.0);
            }
            {
                double sd = (double)vv.z * scaleE;
                double ov = sd * (1.0 - sd * sd);
                double oc = fmin(fmax(ov, -3.0e38), 3.0e38);
                o4.z = (float)((oc == oc) ? oc : 0.0);
            }
            {
                double sd = (double)vv.w * scaleE;
                double ov = sd * (1.0 - sd * sd);
                double oc = fmin(fmax(ov, -3.0e38), 3.0e38);
                o4.w = (float)((oc == oc) ? oc : 0.0);
            }
            *(float4*)(out + ob[r]) = o4;
        }

        if ((t & 7) == 7) {      // periodic rescale (uniform branch)
            float m = mx;
#pragma unroll
            for (int o = 32; o > 0; o >>= 1) m = fmaxf(m, __shfl_xor(m, o));
            if ((tid & 63) == 0) red[tid >> 6] = m;
            __syncthreads();     // closes S-read phase AND publishes red[]
            m = fmaxf(fmaxf(red[0], red[1]), fmaxf(red[2], red[3]));
            if (m > RESCALE_THRESH) {
#pragma unroll
                for (int r = 0; r < 4; ++r) {
                    sn[r].x *= SCL_DN; sn[r].y *= SCL_DN;
                    sn[r].z *= SCL_DN; sn[r].w *= SCL_DN;
                }
                E += 1;
                scaleE *= 0x1p40;
                uscale *= SCL_DN;
            }
        } else {
            __syncthreads();     // close read phase before overwriting S
        }
#pragma unroll
        for (int r = 0; r < 4; ++r) *(float4*)&S[rb + r][j4] = sn[r];
        __syncthreads();
    }
}

// ---------------------------------------------------------------------------
// Fallback (proven path): single-pass sequential recurrence.
// ---------------------------------------------------------------------------
__global__ __launch_bounds__(512) void recur(const float* __restrict__ R,
                                             const float* __restrict__ s0,
                                             float* __restrict__ out,
                                             int T) {
    __shared__ float sbuf[2][512];
    __shared__ float red[512];

    const int b = blockIdx.x;
    const int j = threadIdx.x;

    float sini = s0[(size_t)b * 512 + j];
    sbuf[0][j] = fminf(fmaxf(sini, -LIM), LIM);
    __syncthreads();

    const float* __restrict__ Rc = R + j;
    float* __restrict__ ob = out + (size_t)b * T * 512;

    int cur = 0;
    double scaleE = 1.0;
    float  uscale = 1.0f;

    for (int t = 0; t < T; ++t) {
        const float* s = sbuf[cur];
        float d0 = 0.f, d1 = 0.f, d2 = 0.f, d3 = 0.f;
#pragma unroll 8
        for (int d = 0; d < 512; d += 4) {
            d0 = fmaf(s[d + 0], Rc[(size_t)(d + 0) * 512], d0);
            d1 = fmaf(s[d + 1], Rc[(size_t)(d + 1) * 512], d1);
            d2 = fmaf(s[d + 2], Rc[(size_t)(d + 2) * 512], d2);
            d3 = fmaf(s[d + 3], Rc[(size_t)(d + 3) * 512], d3);
        }
        float u = ob[(size_t)t * 512 + j];
        float snew = fmaf(u, uscale, (d0 + d1) + (d2 + d3));
        snew = fminf(fmaxf(snew, -LIM), LIM);

        double sd = (double)snew * scaleE;
        double ov = sd * (1.0 - sd * sd);
        double oc = fmin(fmax(ov, -3.0e38), 3.0e38);
        oc = (oc == oc) ? oc : 0.0;
        ob[(size_t)t * 512 + j] = (float)oc;

        if ((t & 31) == 31) {
            red[j] = fabsf(snew);
            __syncthreads();
#pragma unroll
            for (int w = 256; w > 0; w >>= 1) {
                if (j < w) red[j] = fmaxf(red[j], red[j + w]);
                __syncthreads();
            }
            float m = red[0];
            __syncthreads();
            if (m > RESCALE_THRESH) {
                snew   *= SCL_DN;
                scaleE *= 0x1p40;
                uscale *= SCL_DN;
            }
        }

        sbuf[cur ^ 1][j] = snew;
        __syncthreads();
        cur ^= 1;
    }
}

// ---------------------------------------------------------------------------
extern "C" void kernel_launch(void* const* d_in, const int* in_sizes, int n_in,
                              void* d_out, int out_size, void* d_ws, size_t ws_size,
                              hipStream_t stream) {
    const float* x  = (const float*)d_in[0];  // [B, T, 512]
    const float* K  = (const float*)d_in[1];  // [512, 512]
    const float* R  = (const float*)d_in[2];  // [512, 512]
    const float* s0 = (const float*)d_in[3];  // [B, 512]
    float* out = (float*)d_out;               // [B, T, 512]

    const int D = 512;
    const int M = in_sizes[0] / D;   // B*T
    const int B = in_sizes[3] / D;   // 64
    const int T = M / B;             // 1024
    const int G  = B / NB;           // 8 batch groups (passA/passB)
    const int Gc = B / NBC;          // 32 combine groups

    // Phase 1: U = X@K into d_out (both paths need it).
    gemm_xk<<<dim3(D / BN, M / BM), 256, 0, stream>>>(x, K, out);

    // Workspace layout (bytes):
    //   [0, 1MB)   RLa (R^2, R^8)
    //   [1, 2MB)   RLb (R^4, R^16)
    //   [2, 10MB)  yeh: CHUNKS slots of B*D floats. Slot c (c<CHUNKS-1) holds
    //              y_end(c), later overwritten in place by h(c+1).
    //              Slot CHUNKS-1 hosts Ebuf (8 KB).
    const size_t MB = 1u << 20;
    const size_t slot = (size_t)B * D * sizeof(float);        // 128 KB
    const size_t off_RLa = 0;
    const size_t off_RLb = 1 * MB;
    const size_t off_yeh = 2 * MB;
    const size_t off_E   = off_yeh + (size_t)(CHUNKS - 1) * slot;
    const size_t need    = off_yeh + (size_t)CHUNKS * slot;   // 10 MB for B=64

    if (ws_size < need || (T % CHUNKS) != 0 || (B % NB) != 0 || (B % NBC) != 0 ||
        D != 512 || (size_t)CHUNKS * Gc * sizeof(int) > slot) {
        // Fallback: proven single-pass path.
        recur<<<B, D, 0, stream>>>(R, s0, out, T);
        return;
    }

    char* ws = (char*)d_ws;
    float* RLa  = (float*)(ws + off_RLa);
    float* RLb  = (float*)(ws + off_RLb);
    float* yeh  = (float*)(ws + off_yeh);
    int*   Ebuf = (int*)(ws + off_E);

    // Phase 2: RL = R^L by repeated squaring (L = T/CHUNKS = 16 = 2^4).
    dim3 sq(D / BN, D / BM);
    gemm_xk<<<sq, 256, 0, stream>>>(R,   R,   RLa);   // R^2
    gemm_xk<<<sq, 256, 0, stream>>>(RLa, RLa, RLb);   // R^4
    gemm_xk<<<sq, 256, 0, stream>>>(RLb, RLb, RLa);   // R^8
    gemm_xk<<<sq, 256, 0, stream>>>(RLa, RLa, RLb);   // R^16

    // Phase 3: local chunk endpoints (chunk CHUNKS-1's endpoint is unused).
    passA<<<dim3(G, CHUNKS - 1), 256, 0, stream>>>(out, R, yeh, T, B);

    // Phase 4: sequential combine across chunks (h in place + per-chunk exponent).
    combine<<<Gc, 512, 0, stream>>>(yeh, s0, RLb, Ebuf, B, CHUNKS);

    // Phase 5: true recurrence per chunk + hopf output.
    passB<<<dim3(G, CHUNKS), 256, 0, stream>>>(R, s0, yeh, Ebuf, out, T, B, Gc);
}